// Round 4
// baseline (279.886 us; speedup 1.0000x reference)
//
#include <hip/hip_runtime.h>
#include <hip/hip_bf16.h>

// EAConv fused: EM-routing aggregation for all T=3 steps + temporal blend,
// one kernel. T=3, b=1, n=50000, d=64, m=16, K=4, dd=16.
// Wave = node; lane = (k,m): m=lane&15 (neighbor), k=lane>>4 (factor).
// Lane holds neighbor m's full 16-dim factor-k row in v2f[8] registers.
// R4: u kept UNNORMALIZED (logits scaled by rsqrt(||u||^2) instead — softmax
// is shift/scale-safe since |dot(zhat,uhat)|<=1), packed fp32 (v_pk_fma_f32)
// for all in-lane math, temporal blend folded in via writer-lane slices.

typedef float v2f __attribute__((ext_vector_type(2)));

constexpr int T  = 3;
constexpr int N  = 50000;
constexpr int D  = 64;
constexpr int M  = 16;
constexpr int DD = 16;
constexpr float EPS2 = 1e-24f;  // (1e-12)^2

template <int CTRL>
__device__ __forceinline__ float dpp_add(float v) {
    int rot = __builtin_amdgcn_update_dpp(
        0, __float_as_int(v), CTRL, 0xF, 0xF, false);
    return v + __int_as_float(rot);
}
// sum over the 16 lanes of a row; result broadcast to every lane of the row
__device__ __forceinline__ float rowsum16(float v) {
    v = dpp_add<0x128>(v);  // row_ror:8
    v = dpp_add<0x124>(v);  // row_ror:4
    v = dpp_add<0x122>(v);  // row_ror:2
    v = dpp_add<0x121>(v);  // row_ror:1
    return v;
}

__global__ __launch_bounds__(256, 6) void eaconv_fused(
    const float* __restrict__ x_all,   // [T,N,D]
    const int*   __restrict__ nbr_all, // [T,N,M]
    float*       __restrict__ out)     // [T,N,D] = blended e-planes
{
    const int wave = (blockIdx.x * blockDim.x + threadIdx.x) >> 6;
    const int lane = threadIdx.x & 63;
    if (wave >= N) return;
    const int i = wave;
    const int m = lane & 15;
    const int k = lane >> 4;

    // blend coefficients (sigmoid(0)=0.5, sigmoid(1)=s1):
    // e0 = U0; e1 = 0.25 U0 + 0.5 U1; e2 = c0 U0 + c1 U1 + 0.5 U2
    const float s1 = 0.7310585786300049f;
    const float c0 = 0.125f + 0.0625f * s1;   // 0.17069116...
    const float c1 = 0.125f * s1;             // 0.09138232...

    float4 acc1 = make_float4(0, 0, 0, 0);    // writer-lane slice of e1
    float4 acc2 = make_float4(0, 0, 0, 0);    // writer-lane slice of e2

#pragma unroll
    for (int t = 0; t < T; ++t) {
        const float* x = x_all + (size_t)t * N * D;

        int j = nbr_all[((size_t)t * N + i) * M + m];
        const bool valid = (unsigned)j < (unsigned)N;
        j = valid ? j : 0;

        const float4* xr = (const float4*)(x + (size_t)i * D + k * DD);
        const float4* zr = (const float4*)(x + (size_t)j * D + k * DD);
        float4 a0 = xr[0], a1 = xr[1], a2 = xr[2], a3 = xr[3];
        float4 b0 = zr[0], b1 = zr[1], b2 = zr[2], b3 = zr[3];
        v2f xk[8] = {{a0.x,a0.y},{a0.z,a0.w},{a1.x,a1.y},{a1.z,a1.w},
                     {a2.x,a2.y},{a2.z,a2.w},{a3.x,a3.y},{a3.z,a3.w}};
        v2f z[8]  = {{b0.x,b0.y},{b0.z,b0.w},{b1.x,b1.y},{b1.z,b1.w},
                     {b2.x,b2.y},{b2.z,b2.w},{b3.x,b3.y},{b3.z,b3.w}};

        // in-lane L2 normalize both rows (zero for invalid neighbor)
        v2f sx = xk[0] * xk[0], sz = z[0] * z[0];
#pragma unroll
        for (int q = 1; q < 8; ++q) {
            sx = __builtin_elementwise_fma(xk[q], xk[q], sx);
            sz = __builtin_elementwise_fma(z[q],  z[q],  sz);
        }
        const float rx = __builtin_amdgcn_rsqf(fmaxf(sx.x + sx.y, EPS2));
        float rz = __builtin_amdgcn_rsqf(fmaxf(sz.x + sz.y, EPS2));
        if (!valid) rz = 0.f;
#pragma unroll
        for (int q = 0; q < 8; ++q) { xk[q] *= rx; z[q] *= rz; }

        // iter 0 (direction only; scale folded into logit): u = sum_m z + 4*xk
        v2f u[8];
#pragma unroll
        for (int q = 0; q < 8; ++q) {
            v2f s;
            s.x = rowsum16(z[q].x);
            s.y = rowsum16(z[q].y);
            u[q] = __builtin_elementwise_fma(xk[q], (v2f)(4.0f), s);
        }
        v2f ns = u[0] * u[0];
#pragma unroll
        for (int q = 1; q < 8; ++q) ns = __builtin_elementwise_fma(u[q], u[q], ns);
        float inv = __builtin_amdgcn_rsqf(fmaxf(ns.x + ns.y, EPS2));

        // iters 1..2
#pragma unroll
        for (int it = 1; it < 3; ++it) {
            v2f da = z[0] * u[0];
#pragma unroll
            for (int q = 1; q < 8; ++q) da = __builtin_elementwise_fma(z[q], u[q], da);
            const float logit = (da.x + da.y) * inv;   // in [-1,1]: no max-sub
            const float e = __expf(logit);
            float es = e + __shfl_xor(e, 16, 64);
            es += __shfl_xor(es, 32, 64);
            const float w = e * __builtin_amdgcn_rcpf(es);
#pragma unroll
            for (int q = 0; q < 8; ++q) {
                v2f wz = z[q] * w;
                v2f s;
                s.x = rowsum16(wz.x);
                s.y = rowsum16(wz.y);
                u[q] = xk[q] + s;
            }
            if (it < 2) {
                v2f na = u[0] * u[0];
#pragma unroll
                for (int q = 1; q < 8; ++q) na = __builtin_elementwise_fma(u[q], u[q], na);
                inv = __builtin_amdgcn_rsqf(fmaxf(na.x + na.y, EPS2));
            }
        }

        // writer-lane float4 slice of U_t (lanes m=0..3 of each k-row)
        float4 sl = make_float4(0, 0, 0, 0);
        if      (m == 0) sl = make_float4(u[0].x, u[0].y, u[1].x, u[1].y);
        else if (m == 1) sl = make_float4(u[2].x, u[2].y, u[3].x, u[3].y);
        else if (m == 2) sl = make_float4(u[4].x, u[4].y, u[5].x, u[5].y);
        else if (m == 3) sl = make_float4(u[6].x, u[6].y, u[7].x, u[7].y);

        float4* op = (float4*)(out + ((size_t)t * N + i) * D + k * DD) + m;
        if (t == 0) {
            if (m < 4) *op = sl;          // e0 = U0
            acc1 = make_float4(0.25f*sl.x, 0.25f*sl.y, 0.25f*sl.z, 0.25f*sl.w);
            acc2 = make_float4(c0*sl.x, c0*sl.y, c0*sl.z, c0*sl.w);
        } else if (t == 1) {
            acc1.x = fmaf(0.5f, sl.x, acc1.x);
            acc1.y = fmaf(0.5f, sl.y, acc1.y);
            acc1.z = fmaf(0.5f, sl.z, acc1.z);
            acc1.w = fmaf(0.5f, sl.w, acc1.w);
            if (m < 4) *op = acc1;        // e1
            acc2.x = fmaf(c1, sl.x, acc2.x);
            acc2.y = fmaf(c1, sl.y, acc2.y);
            acc2.z = fmaf(c1, sl.z, acc2.z);
            acc2.w = fmaf(c1, sl.w, acc2.w);
        } else {
            acc2.x = fmaf(0.5f, sl.x, acc2.x);
            acc2.y = fmaf(0.5f, sl.y, acc2.y);
            acc2.z = fmaf(0.5f, sl.z, acc2.z);
            acc2.w = fmaf(0.5f, sl.w, acc2.w);
            if (m < 4) *op = acc2;        // e2
        }
    }
}

extern "C" void kernel_launch(void* const* d_in, const int* in_sizes, int n_in,
                              void* d_out, int out_size, void* d_ws, size_t ws_size,
                              hipStream_t stream) {
    const float* x_all = (const float*)d_in[0];
    const int*   nbrs  = (const int*)d_in[1];
    float*       out   = (float*)d_out;

    // one wave per node: 50000 waves, 4 waves/block -> 12500 blocks
    const int total_threads = N * 64;
    eaconv_fused<<<(total_threads + 255) / 256, 256, 0, stream>>>(x_all, nbrs, out);
}

// Round 5
// 255.151 us; speedup vs baseline: 1.0969x; 1.0969x over previous
//
#include <hip/hip_runtime.h>
#include <hip/hip_bf16.h>

// EAConv: EM-routing neighbor aggregation + temporal blend.
// T=3, b=1, n=50000, d=64, m=16, K=4, dd=16.
// R5 = R3 two-kernel structure (measured-clean memory behavior: FETCH 236MB,
// WRITE 37.5MB) + R4 VALU improvements (packed v_pk_fma_f32, u kept
// unnormalized with rsqrt folded into the logit, no softmax max-subtract).
// Wave = (t,node); lane = (k,m): m=lane&15 neighbor, k=lane>>4 factor.
// Lane holds neighbor m's full 16-dim factor-k row in v2f[8] registers.

typedef float v2f __attribute__((ext_vector_type(2)));

constexpr int T  = 3;
constexpr int N  = 50000;
constexpr int D  = 64;
constexpr int M  = 16;
constexpr int DD = 16;
constexpr float EPS2 = 1e-24f;  // (1e-12)^2

template <int CTRL>
__device__ __forceinline__ float dpp_add(float v) {
    // v + (v rotated within the 16-lane row); single v_add_f32 dpp
    int rot = __builtin_amdgcn_update_dpp(
        0, __float_as_int(v), CTRL, 0xF, 0xF, false);
    return v + __int_as_float(rot);
}
// sum over the 16 lanes of a row; result broadcast to every lane of the row
__device__ __forceinline__ float rowsum16(float v) {
    v = dpp_add<0x128>(v);  // row_ror:8
    v = dpp_add<0x124>(v);  // row_ror:4
    v = dpp_add<0x122>(v);  // row_ror:2
    v = dpp_add<0x121>(v);  // row_ror:1
    return v;
}

__global__ __launch_bounds__(256) void eaconv_agg(
    const float* __restrict__ x_all,   // [T,N,D]
    const int*   __restrict__ nbr_all, // [T,N,M]
    float*       __restrict__ out)     // [T,N,D] <- U_t (pre-blend)
{
    const int wave = (blockIdx.x * blockDim.x + threadIdx.x) >> 6;
    const int lane = threadIdx.x & 63;
    if (wave >= T * N) return;
    const int t = wave / N;
    const int i = wave - t * N;
    const int m = lane & 15;
    const int k = lane >> 4;

    const float* x = x_all + (size_t)t * N * D;

    int j = nbr_all[((size_t)t * N + i) * M + m];
    const bool valid = (unsigned)j < (unsigned)N;
    j = valid ? j : 0;

    // own factor row (broadcast addr across row) + neighbor row (scattered)
    const float4* xr = (const float4*)(x + (size_t)i * D + k * DD);
    const float4* zr = (const float4*)(x + (size_t)j * D + k * DD);
    float4 a0 = xr[0], a1 = xr[1], a2 = xr[2], a3 = xr[3];
    float4 b0 = zr[0], b1 = zr[1], b2 = zr[2], b3 = zr[3];
    v2f xk[8] = {{a0.x,a0.y},{a0.z,a0.w},{a1.x,a1.y},{a1.z,a1.w},
                 {a2.x,a2.y},{a2.z,a2.w},{a3.x,a3.y},{a3.z,a3.w}};
    v2f z[8]  = {{b0.x,b0.y},{b0.z,b0.w},{b1.x,b1.y},{b1.z,b1.w},
                 {b2.x,b2.y},{b2.z,b2.w},{b3.x,b3.y},{b3.z,b3.w}};

    // in-lane L2 normalize both rows (zero row for invalid neighbor)
    v2f sx = xk[0] * xk[0], sz = z[0] * z[0];
#pragma unroll
    for (int q = 1; q < 8; ++q) {
        sx = __builtin_elementwise_fma(xk[q], xk[q], sx);
        sz = __builtin_elementwise_fma(z[q],  z[q],  sz);
    }
    const float rx = __builtin_amdgcn_rsqf(fmaxf(sx.x + sx.y, EPS2));
    float rz = __builtin_amdgcn_rsqf(fmaxf(sz.x + sz.y, EPS2));
    if (!valid) rz = 0.f;
#pragma unroll
    for (int q = 0; q < 8; ++q) { xk[q] *= rx; z[q] *= rz; }

    // iter 0 (direction only; scale folds into logit): u = sum_m z + 4*xk
    v2f u[8];
#pragma unroll
    for (int q = 0; q < 8; ++q) {
        v2f s;
        s.x = rowsum16(z[q].x);
        s.y = rowsum16(z[q].y);
        u[q] = __builtin_elementwise_fma(xk[q], (v2f)(4.0f), s);
    }
    v2f ns = u[0] * u[0];
#pragma unroll
    for (int q = 1; q < 8; ++q) ns = __builtin_elementwise_fma(u[q], u[q], ns);
    float inv = __builtin_amdgcn_rsqf(fmaxf(ns.x + ns.y, EPS2));

    // iters 1..2
#pragma unroll
    for (int it = 1; it < 3; ++it) {
        v2f da = z[0] * u[0];
#pragma unroll
        for (int q = 1; q < 8; ++q) da = __builtin_elementwise_fma(z[q], u[q], da);
        const float logit = (da.x + da.y) * inv;   // in [-1,1]: no max-sub
        const float e = __expf(logit);
        float es = e + __shfl_xor(e, 16, 64);
        es += __shfl_xor(es, 32, 64);
        const float w = e * __builtin_amdgcn_rcpf(es);
#pragma unroll
        for (int q = 0; q < 8; ++q) {
            v2f wz = z[q] * w;
            v2f s;
            s.x = rowsum16(wz.x);
            s.y = rowsum16(wz.y);
            u[q] = xk[q] + s;
        }
        if (it < 2) {  // no normalize after the last iteration
            v2f na = u[0] * u[0];
#pragma unroll
            for (int q = 1; q < 8; ++q) na = __builtin_elementwise_fma(u[q], u[q], na);
            inv = __builtin_amdgcn_rsqf(fmaxf(na.x + na.y, EPS2));
        }
    }

    // store (R3 pattern — measured-clean 37.5 MB write traffic):
    // u replicated across each row; lanes m=0..3 write one float4 each
    float* o = out + ((size_t)t * N + i) * D + k * DD;
    if (m == 0) ((float4*)o)[0] = make_float4(u[0].x, u[0].y, u[1].x, u[1].y);
    if (m == 1) ((float4*)o)[1] = make_float4(u[2].x, u[2].y, u[3].x, u[3].y);
    if (m == 2) ((float4*)o)[2] = make_float4(u[4].x, u[4].y, u[5].x, u[5].y);
    if (m == 3) ((float4*)o)[3] = make_float4(u[6].x, u[6].y, u[7].x, u[7].y);
}

// Temporal blend, closed form (sigmoid(0)=0.5, sigmoid(1)=0.7310585786):
//   e0 = u0;  e1 = 0.25*e0 + 0.5*u1;  e2 = (0.5*e0 + s1*e1)*0.25 + 0.5*u2
__global__ __launch_bounds__(256) void eaconv_combine(float* __restrict__ out) {
    const int nd4 = N * D / 4;
    int idx = blockIdx.x * blockDim.x + threadIdx.x;
    if (idx >= nd4) return;
    float4* o = (float4*)out;
    float4 u0 = o[idx];
    float4 u1 = o[nd4 + idx];
    float4 u2 = o[2 * nd4 + idx];
    const float s1 = 0.7310585786300049f;
    float4 e1, e2;
    e1.x = 0.25f * u0.x + 0.5f * u1.x;
    e1.y = 0.25f * u0.y + 0.5f * u1.y;
    e1.z = 0.25f * u0.z + 0.5f * u1.z;
    e1.w = 0.25f * u0.w + 0.5f * u1.w;
    e2.x = (0.5f * u0.x + s1 * e1.x) * 0.25f + 0.5f * u2.x;
    e2.y = (0.5f * u0.y + s1 * e1.y) * 0.25f + 0.5f * u2.y;
    e2.z = (0.5f * u0.z + s1 * e1.z) * 0.25f + 0.5f * u2.z;
    e2.w = (0.5f * u0.w + s1 * e1.w) * 0.25f + 0.5f * u2.w;
    o[nd4 + idx] = e1;
    o[2 * nd4 + idx] = e2;
}

extern "C" void kernel_launch(void* const* d_in, const int* in_sizes, int n_in,
                              void* d_out, int out_size, void* d_ws, size_t ws_size,
                              hipStream_t stream) {
    const float* x_all = (const float*)d_in[0];
    const int*   nbrs  = (const int*)d_in[1];
    float*       out   = (float*)d_out;

    const int total_threads = T * N * 64;  // one wave per (t,node)
    eaconv_agg<<<(total_threads + 255) / 256, 256, 0, stream>>>(x_all, nbrs, out);
    eaconv_combine<<<(N * D / 4 + 255) / 256, 256, 0, stream>>>(out);
}